// Round 2
// baseline (176.738 us; speedup 1.0000x reference)
//
#include <hip/hip_runtime.h>

// LinkPredictor: out[e] = W2 . relu(W1s.z[src] + W1d.z[dst] + b1) + b2
// Factored: C = z @ [W1s|W1d]^T  (node-level GEMM, bf16 MFMA),
// then per-edge gather + fused add/relu/dot.

#define NN 100000   // nodes
#define NE 300000   // edges
#define KD 256      // in channels (K)
#define NO 512      // 2*HID output cols of node GEMM (A | B)

#define BM 128
#define BN 128
#define MTILES 782  // ceil(100000/128)

typedef __attribute__((ext_vector_type(8))) short short8;
typedef __attribute__((ext_vector_type(4))) short short4v;
typedef __attribute__((ext_vector_type(8))) unsigned short ushort8;
typedef __attribute__((ext_vector_type(4))) float f32x4;

__device__ __forceinline__ unsigned short f2bf(float f) {
  union { float f; unsigned int u; } v; v.f = f;
  unsigned int u = v.u;
  u += 0x7fffu + ((u >> 16) & 1u);   // RNE
  return (unsigned short)(u >> 16);
}
__device__ __forceinline__ float bf2f(unsigned short h) {
  union { unsigned int u; float f; } v; v.u = ((unsigned int)h) << 16;
  return v.f;
}

// ---- repack W1 (f32 [256][512]) -> Wt (bf16 [512][256], K-contiguous) ----
// Wt[j][k] = (j<256) ? W1[j][k] : W1[j-256][256+k]
__global__ void prep_w(const float* __restrict__ W1, unsigned short* __restrict__ Wt) {
  int idx = blockIdx.x * 256 + threadIdx.x;   // 512*256 = 131072 total
  int j = idx >> 8, k = idx & 255;
  float v = (j < 256) ? W1[j * 512 + k] : W1[(j - 256) * 512 + 256 + k];
  Wt[idx] = f2bf(v);
}

// ---- C[n][j] = sum_k z[n][k] * Wt[j][k]  (bf16 MFMA, f32 acc) ----
// Full-K in LDS (A only, XOR-swizzled), B direct from L2, one barrier.
__global__ __launch_bounds__(256, 2) void gemm_zw(const float* __restrict__ z,
                                                  const unsigned short* __restrict__ Wt,
                                                  unsigned short* __restrict__ C) {
  __shared__ unsigned short As[BM * KD];   // 64 KB, chunk-swizzled

  // XCD-pinned mapping: 4 n-tile siblings of one m-tile share g%8 (same XCD)
  const int g = blockIdx.x;
  const int xcd = g & 7;
  const int s = g >> 3;
  const int mt = (s >> 2) * 8 + xcd;
  const int nt = s & 3;
  if (mt >= MTILES) return;
  const int gm0 = mt * BM;
  const int n0 = nt * BN;

  const int t = threadIdx.x;
  const int wave = t >> 6, lane = t & 63;
  const int wm = wave >> 1, wn = wave & 1;       // 2x2 wave grid, 64x64 each
  const int l15 = lane & 15, l4 = lane >> 4;

  // ---- stage A: 32 passes, each wave writes one row (1 KB contiguous read)
  // LDS layout: row*256 shorts; 16B chunk c stored at chunk (c ^ (row&7))
  {
    const int srow = t >> 6;           // wave id = row offset within pass group
    const int scol = (t & 63) * 4;     // f32 index within row
    const int chunkb = (t & 63) >> 1;  // 16B chunk index (0..31)
    const int half = (t & 1) * 4;      // short offset within chunk
#pragma unroll 4
    for (int pass = 0; pass < 32; ++pass) {
      const int row = pass * 4 + srow;
      const int grow = gm0 + row;
      float4 v;
      if (grow < NN) v = *(const float4*)(z + (size_t)grow * KD + scol);
      else { v.x = 0.f; v.y = 0.f; v.z = 0.f; v.w = 0.f; }
      short4v sv;
      sv[0] = (short)f2bf(v.x); sv[1] = (short)f2bf(v.y);
      sv[2] = (short)f2bf(v.z); sv[3] = (short)f2bf(v.w);
      const int chunk = chunkb ^ (row & 7);
      *(short4v*)&As[row * KD + chunk * 8 + half] = sv;
    }
  }
  __syncthreads();

  f32x4 acc[4][4];
#pragma unroll
  for (int m = 0; m < 4; ++m)
#pragma unroll
    for (int n = 0; n < 4; ++n) acc[m][n] = (f32x4)0.f;

  // B fragment base: rows (n0 + wn*64 + n*16 + l15), k-chunk l4*8 + ks*32
  const unsigned short* wb = Wt + (size_t)(n0 + wn * 64 + l15) * KD + l4 * 8;
  const int xorv = l15 & 7;
  const int arow = wm * 64 + l15;

#pragma unroll
  for (int ks = 0; ks < 8; ++ks) {
    short8 af[4], bf[4];
#pragma unroll
    for (int m = 0; m < 4; ++m) {
      const int chunk = ((ks << 2) | l4) ^ xorv;
      af[m] = *(const short8*)&As[(arow + m * 16) * KD + chunk * 8];
    }
#pragma unroll
    for (int n = 0; n < 4; ++n)
      bf[n] = *(const short8*)(wb + (size_t)n * 16 * KD + ks * 32);
#pragma unroll
    for (int m = 0; m < 4; ++m)
#pragma unroll
      for (int n = 0; n < 4; ++n)
        acc[m][n] = __builtin_amdgcn_mfma_f32_16x16x32_bf16(af[m], bf[n], acc[m][n], 0, 0, 0);
  }

  // epilogue: C/D layout col = lane&15, row = (lane>>4)*4 + r  (m89-verified)
#pragma unroll
  for (int m = 0; m < 4; ++m) {
#pragma unroll
    for (int r = 0; r < 4; ++r) {
      const int grow = gm0 + wm * 64 + m * 16 + l4 * 4 + r;
      if (grow < NN) {
        const size_t base = (size_t)grow * NO + n0 + wn * 64 + l15;
#pragma unroll
        for (int n = 0; n < 4; ++n)
          C[base + n * 16] = f2bf(acc[m][n][r]);
      }
    }
  }
}

// ---- per-edge: out[e] = b2 + sum_i W2[i]*relu(A[s][i] + B[d][i] + b1[i]) ----
// 16 lanes per edge, 16 channels per lane (two 32B gathered bf16 loads/lane).
__global__ __launch_bounds__(256) void edge_mlp(const unsigned short* __restrict__ C,
                                                const int* __restrict__ ei,
                                                const float* __restrict__ b1,
                                                const float* __restrict__ W2,
                                                const float* __restrict__ b2,
                                                float* __restrict__ out) {
  const int t = threadIdx.x;
  const int lane = t & 63;
  const int g = lane >> 4;           // edge slot within wave (0..3)
  const int c0 = (lane & 15) * 16;   // channel base for this lane
  float b1v[16], w2v[16];
#pragma unroll
  for (int i = 0; i < 16; ++i) { b1v[i] = b1[c0 + i]; w2v[i] = W2[c0 + i]; }
  const float bias2 = b2[0];
  const int waveId = blockIdx.x * 4 + (t >> 6);
  const int nw = gridDim.x * 4;
  for (int e0 = waveId * 4; e0 < NE; e0 += nw * 4) {
    const int e = e0 + g;                 // NE % 4 == 0 -> always valid
    const int s = ei[e];
    const int d = ei[NE + e];
    const ushort8* ap = (const ushort8*)(C + (size_t)s * NO + c0);
    const ushort8* bp = (const ushort8*)(C + (size_t)d * NO + 256 + c0);
    ushort8 a0 = ap[0], a1 = ap[1];
    ushort8 v0 = bp[0], v1 = bp[1];
    float partial = 0.f;
#pragma unroll
    for (int j = 0; j < 8; ++j) {
      float h = bf2f(a0[j]) + bf2f(v0[j]) + b1v[j];
      h = fmaxf(h, 0.f);
      partial = fmaf(h, w2v[j], partial);
    }
#pragma unroll
    for (int j = 0; j < 8; ++j) {
      float h = bf2f(a1[j]) + bf2f(v1[j]) + b1v[8 + j];
      h = fmaxf(h, 0.f);
      partial = fmaf(h, w2v[8 + j], partial);
    }
    partial += __shfl_xor(partial, 8);
    partial += __shfl_xor(partial, 4);
    partial += __shfl_xor(partial, 2);
    partial += __shfl_xor(partial, 1);
    if ((lane & 15) == 0) out[e] = partial + bias2;
  }
}

extern "C" void kernel_launch(void* const* d_in, const int* in_sizes, int n_in,
                              void* d_out, int out_size, void* d_ws, size_t ws_size,
                              hipStream_t stream) {
  const float* z  = (const float*)d_in[0];
  const float* W1 = (const float*)d_in[1];
  const float* b1 = (const float*)d_in[2];
  const float* W2 = (const float*)d_in[3];
  const float* b2 = (const float*)d_in[4];
  const int*   ei = (const int*)d_in[5];
  float* out = (float*)d_out;

  unsigned short* C  = (unsigned short*)d_ws;          // 100000*512 bf16 = 102.4 MB
  unsigned short* Wt = C + (size_t)NN * NO;            // 512*256 bf16 = 256 KB

  prep_w<<<512, 256, 0, stream>>>(W1, Wt);
  // XCD-pinned grid: 98 slot-groups * 4 ntiles * 8 xcds = 3136 (2 idle)
  gemm_zw<<<3136, 256, 0, stream>>>(z, Wt, C);
  edge_mlp<<<2048, 256, 0, stream>>>(C, ei, b1, W2, b2, out);
}

// Round 3
// 128.900 us; speedup vs baseline: 1.3711x; 1.3711x over previous
//
#include <hip/hip_runtime.h>

// LinkPredictor: out[e] = W2 . relu(W1s.z[src] + W1d.z[dst] + b1) + b2
// Factored: C = z @ [W1s|W1d]^T  (node-level GEMM, bf16 MFMA),
// then per-edge gather + fused add/relu/dot.

#define NN 100000   // nodes
#define NE 300000   // edges
#define KD 256      // in channels (K)
#define NO 512      // 2*HID output cols of node GEMM (A | B)

#define BM 128
#define BN 128
#define BK 32
#define NIT 8       // KD/BK
#define MTILES 782  // ceil(100000/128)

typedef __attribute__((ext_vector_type(8))) short short8;
typedef __attribute__((ext_vector_type(8))) unsigned short ushort8;
typedef __attribute__((ext_vector_type(4))) float f32x4;
typedef __attribute__((ext_vector_type(4))) unsigned int uint4v;

__device__ __forceinline__ unsigned short f2bf(float f) {
  union { float f; unsigned int u; } v; v.f = f;
  unsigned int u = v.u;
  u += 0x7fffu + ((u >> 16) & 1u);   // RNE
  return (unsigned short)(u >> 16);
}
__device__ __forceinline__ float bf2f(unsigned short h) {
  union { unsigned int u; float f; } v; v.u = ((unsigned int)h) << 16;
  return v.f;
}
// pack 2 f32 -> 2 bf16 (round-half-up: +0x8000 then take hi16 via v_perm)
__device__ __forceinline__ unsigned int pkbf(float a, float b) {
  unsigned int ua = __float_as_uint(a) + 0x8000u;
  unsigned int ub = __float_as_uint(b) + 0x8000u;
  return __builtin_amdgcn_perm(ub, ua, 0x07060302u);  // {ua.hi16, ub.hi16}
}

// ---- repack W1 (f32 [256][512]) -> Wt (bf16 [512][256], K-contiguous) ----
__global__ void prep_w(const float* __restrict__ W1, unsigned short* __restrict__ Wt) {
  int idx = blockIdx.x * 256 + threadIdx.x;   // 512*256 = 131072 total
  int j = idx >> 8, k = idx & 255;
  float v = (j < 256) ? W1[j * 512 + k] : W1[(j - 256) * 512 + 256 + k];
  Wt[idx] = f2bf(v);
}

// ---- C[n][j] = sum_k z[n][k] * Wt[j][k]  (bf16 MFMA, f32 acc) ----
// m97-style: A (f32) via global_load_lds dbuf w/ pre-swizzled source,
// B fragments direct from L2 into registers (1 iter ahead), 1 barrier/iter.
__global__ __launch_bounds__(256, 3) void gemm_zw(const float* __restrict__ z,
                                                  const unsigned short* __restrict__ Wt,
                                                  unsigned short* __restrict__ C) {
  __shared__ float As[2][BM * BK];   // 2 x 16 KB

  // XCD-pinned mapping: 4 n-tile siblings of one m-tile share g%8 (same XCD)
  const int g = blockIdx.x;
  const int xcd = g & 7;
  const int s = g >> 3;
  const int mt = (s >> 2) * 8 + xcd;
  const int nt = s & 3;
  if (mt >= MTILES) return;
  const int gm0 = mt * BM;
  const int n0 = nt * BN;

  const int t = threadIdx.x;
  const int wave = t >> 6, lane = t & 63;
  const int wm = wave >> 1, wn = wave & 1;       // 2x2 wave grid, 64x64 each
  const int l15 = lane & 15, l4 = lane >> 4;

  // --- A-stage descriptors: 4 gll issues/wave, each 1 KB = 8 rows x 128 B.
  // LDS linear in lane order; source chunk pre-swizzled: lane fetches global
  // chunk ((lane&7)^(lane>>3)) of row (issue*8 + lane>>3).
  const char* ga[4];
#pragma unroll
  for (int j = 0; j < 4; ++j) {
    const int row = (((wave << 2) + j) << 3) | (lane >> 3);
    int grow = gm0 + row; if (grow > NN - 1) grow = NN - 1;   // clamp (pad rows unused)
    ga[j] = (const char*)(z + (size_t)grow * KD + (((lane & 7) ^ (lane >> 3)) << 2));
  }
#define STAGE_A(i, b)                                                              \
  {                                                                                \
    _Pragma("unroll")                                                              \
    for (int j = 0; j < 4; ++j)                                                    \
      __builtin_amdgcn_global_load_lds(                                            \
          (const __attribute__((address_space(1))) unsigned int*)(ga[j] + (i) * 128), \
          (__attribute__((address_space(3))) unsigned int*)&As[b][((wave << 2) + j) << 8], \
          16, 0, 0);                                                               \
  }

  // --- B fragment pointers: row (n0+wn*64+n*16+l15), k-offset l4*8 + i*32
  const unsigned short* wb = Wt + (size_t)(n0 + wn * 64 + l15) * KD + l4 * 8;

  ushort8 br0[4], br1[4];
#define LOAD_B(dst, i)                                                             \
  {                                                                                \
    _Pragma("unroll")                                                              \
    for (int n = 0; n < 4; ++n)                                                    \
      dst[n] = *(const ushort8*)(wb + (size_t)n * 16 * KD + (i) * BK);             \
  }

  f32x4 acc[4][4];
#pragma unroll
  for (int m = 0; m < 4; ++m)
#pragma unroll
    for (int n = 0; n < 4; ++n) acc[m][n] = (f32x4)0.f;

  STAGE_A(0, 0);
  LOAD_B(br0, 0);
  __syncthreads();

#pragma unroll
  for (int i = 0; i < NIT; ++i) {
    const int cur = i & 1;
    if (i < NIT - 1) {
      STAGE_A(i + 1, cur ^ 1);
      if (cur) { LOAD_B(br0, i + 1); } else { LOAD_B(br1, i + 1); }
    }
    // compute(i): A frags from LDS (f32, swizzled) -> bf16 pack -> MFMA
    const float* Ab = As[cur];
    short8 af[4];
#pragma unroll
    for (int m = 0; m < 4; ++m) {
      const int r = wm * 64 + m * 16 + l15;
      const int c1 = (l4 << 1) ^ (r & 7);
      const int c2 = ((l4 << 1) | 1) ^ (r & 7);
      const float4 fa = *(const float4*)&Ab[r * BK + (c1 << 2)];
      const float4 fb = *(const float4*)&Ab[r * BK + (c2 << 2)];
      uint4v p;
      p[0] = pkbf(fa.x, fa.y); p[1] = pkbf(fa.z, fa.w);
      p[2] = pkbf(fb.x, fb.y); p[3] = pkbf(fb.z, fb.w);
      union { uint4v u; short8 s; } cv; cv.u = p;
      af[m] = cv.s;
    }
#pragma unroll
    for (int m = 0; m < 4; ++m)
#pragma unroll
      for (int n = 0; n < 4; ++n) {
        union { ushort8 u; short8 s; } bv; bv.u = cur ? br1[n] : br0[n];
        acc[m][n] = __builtin_amdgcn_mfma_f32_16x16x32_bf16(af[m], bv.s, acc[m][n], 0, 0, 0);
      }
    if (i < NIT - 1) __syncthreads();
  }

  // epilogue: C/D layout col = lane&15, row = (lane>>4)*4 + r  (m89-verified)
#pragma unroll
  for (int m = 0; m < 4; ++m) {
#pragma unroll
    for (int r = 0; r < 4; ++r) {
      const int grow = gm0 + wm * 64 + m * 16 + l4 * 4 + r;
      if (grow < NN) {
        const size_t base = (size_t)grow * NO + n0 + wn * 64 + l15;
#pragma unroll
        for (int n = 0; n < 4; ++n)
          C[base + n * 16] = f2bf(acc[m][n][r]);
      }
    }
  }
}

// ---- per-edge: out[e] = b2 + sum_i W2[i]*relu(A[s][i] + B[d][i] + b1[i]) ----
// 16 lanes per edge, 16 channels per lane (two 32B gathered bf16 loads/lane).
__global__ __launch_bounds__(256) void edge_mlp(const unsigned short* __restrict__ C,
                                                const int* __restrict__ ei,
                                                const float* __restrict__ b1,
                                                const float* __restrict__ W2,
                                                const float* __restrict__ b2,
                                                float* __restrict__ out) {
  const int t = threadIdx.x;
  const int lane = t & 63;
  const int g = lane >> 4;           // edge slot within wave (0..3)
  const int c0 = (lane & 15) * 16;   // channel base for this lane
  float b1v[16], w2v[16];
#pragma unroll
  for (int i = 0; i < 16; ++i) { b1v[i] = b1[c0 + i]; w2v[i] = W2[c0 + i]; }
  const float bias2 = b2[0];
  const int waveId = blockIdx.x * 4 + (t >> 6);
  const int nw = gridDim.x * 4;
  for (int e0 = waveId * 4; e0 < NE; e0 += nw * 4) {
    const int e = e0 + g;                 // NE % 4 == 0 -> always valid
    const int s = ei[e];
    const int d = ei[NE + e];
    const ushort8* ap = (const ushort8*)(C + (size_t)s * NO + c0);
    const ushort8* bp = (const ushort8*)(C + (size_t)d * NO + 256 + c0);
    ushort8 a0 = ap[0], a1 = ap[1];
    ushort8 v0 = bp[0], v1 = bp[1];
    float partial = 0.f;
#pragma unroll
    for (int j = 0; j < 8; ++j) {
      float h = bf2f(a0[j]) + bf2f(v0[j]) + b1v[j];
      h = fmaxf(h, 0.f);
      partial = fmaf(h, w2v[j], partial);
    }
#pragma unroll
    for (int j = 0; j < 8; ++j) {
      float h = bf2f(a1[j]) + bf2f(v1[j]) + b1v[8 + j];
      h = fmaxf(h, 0.f);
      partial = fmaf(h, w2v[8 + j], partial);
    }
    partial += __shfl_xor(partial, 8);
    partial += __shfl_xor(partial, 4);
    partial += __shfl_xor(partial, 2);
    partial += __shfl_xor(partial, 1);
    if ((lane & 15) == 0) out[e] = partial + bias2;
  }
}

extern "C" void kernel_launch(void* const* d_in, const int* in_sizes, int n_in,
                              void* d_out, int out_size, void* d_ws, size_t ws_size,
                              hipStream_t stream) {
  const float* z  = (const float*)d_in[0];
  const float* W1 = (const float*)d_in[1];
  const float* b1 = (const float*)d_in[2];
  const float* W2 = (const float*)d_in[3];
  const float* b2 = (const float*)d_in[4];
  const int*   ei = (const int*)d_in[5];
  float* out = (float*)d_out;

  unsigned short* C  = (unsigned short*)d_ws;          // 100000*512 bf16 = 102.4 MB
  unsigned short* Wt = C + (size_t)NN * NO;            // 512*256 bf16 = 256 KB

  prep_w<<<512, 256, 0, stream>>>(W1, Wt);
  // XCD-pinned grid: 98 slot-groups * 4 ntiles * 8 xcds = 3136 (2 idle)
  gemm_zw<<<3136, 256, 0, stream>>>(z, Wt, C);
  edge_mlp<<<2048, 256, 0, stream>>>(C, ei, b1, W2, b2, out);
}

// Round 4
// 124.440 us; speedup vs baseline: 1.4203x; 1.0358x over previous
//
#include <hip/hip_runtime.h>

// LinkPredictor: out[e] = W2 . relu(W1s.z[src] + W1d.z[dst] + b1) + b2
// Factored: C = z @ [W1s|W1d]^T  (node GEMM, bf16 MFMA), then per-edge
// gather + fused add/relu/dot.  GEMM structure: B staged ONCE in LDS
// (64 KB, swizzled), A streamed global->reg, zero per-K barriers.

#define NN 100000   // nodes (= 6250 bands of 16)
#define NE 300000   // edges
#define KD 256      // in channels (K)
#define NO 512      // 2*HID output cols (A | B)
#define BN 128      // cols per block

typedef __attribute__((ext_vector_type(8))) short short8;
typedef __attribute__((ext_vector_type(8))) unsigned short ushort8;
typedef __attribute__((ext_vector_type(4))) float f32x4;
typedef __attribute__((ext_vector_type(4))) unsigned int uint4v;

__device__ __forceinline__ unsigned short f2bf(float f) {
  union { float f; unsigned int u; } v; v.f = f;
  unsigned int u = v.u;
  u += 0x7fffu + ((u >> 16) & 1u);   // RNE
  return (unsigned short)(u >> 16);
}
__device__ __forceinline__ float bf2f(unsigned short h) {
  union { unsigned int u; float f; } v; v.u = ((unsigned int)h) << 16;
  return v.f;
}
// pack 2 f32 -> {bf16(a) low, bf16(b) high} (round-half-up)
__device__ __forceinline__ unsigned int pkbf(float a, float b) {
  unsigned int ua = __float_as_uint(a) + 0x8000u;
  unsigned int ub = __float_as_uint(b) + 0x8000u;
  return __builtin_amdgcn_perm(ub, ua, 0x07060302u);
}
// stored-col -> hidden-channel permutation (within 0..255)
__device__ __forceinline__ int hperm(int s) {
  int j = s & 127;
  return (s & ~127) + ((j & 7) << 4) + (j >> 3);
}

// ---- repack W1 (f32 [256][512]) -> Wt (bf16 [512][256], K-contiguous) ----
__global__ void prep_w(const float* __restrict__ W1, unsigned short* __restrict__ Wt) {
  int idx = blockIdx.x * 256 + threadIdx.x;   // 512*256 = 131072
  int j = idx >> 8, k = idx & 255;
  float v = (j < 256) ? W1[j * 512 + k] : W1[(j - 256) * 512 + 256 + k];
  Wt[idx] = f2bf(v);
}

// ---- C[n][perm(j)] = sum_k z[n][k] * Wt[j][k] ----
__global__ __launch_bounds__(256, 2) void gemm_zw(const float* __restrict__ z,
                                                  const unsigned short* __restrict__ Wt,
                                                  unsigned short* __restrict__ C) {
  __shared__ unsigned short Bs[BN * KD];   // 64 KB

  // XCD-pinned: 4 nt-siblings of one m-group share blockIdx&7 (same XCD)
  const int b = blockIdx.x;
  const int xcd = b & 7;
  const int s = b >> 3;                // 0..127
  const int nt = s & 3;
  const int mg = xcd * 32 + (s >> 2);  // 0..255
  const int n0 = nt * BN;

  const int t = threadIdx.x;
  const int w = t >> 6, lane = t & 63;
  const int l15 = lane & 15, l4 = lane >> 4;

  // ---- stage B once: Bs[row][chunk c stored at c^(row&7)], coalesced src
  for (int i = 0; i < 16; ++i) {
    const int id = t + 256 * i;        // 0..4095 16B-chunks
    const int row = id >> 5, c = id & 31;
    ushort8 v = *(const ushort8*)(Wt + (size_t)(n0 + row) * KD + c * 8);
    *(ushort8*)&Bs[row * KD + ((c ^ (row & 7)) << 3)] = v;
  }
  __syncthreads();                     // the ONLY barrier

  const int strm = mg * 4 + w;         // 0..1023 independent wave streams

  for (int g = 0; g < 4; ++g) {
    const int b0 = strm + 2048 * g;
    if (b0 >= 6250) break;
    int b1 = b0 + 1024;
    if (b1 >= 6250) b1 = b0;           // tail: duplicate (benign re-store)

    f32x4 acc0[8], acc1[8];
#pragma unroll
    for (int n = 0; n < 8; ++n) { acc0[n] = (f32x4)0.f; acc1[n] = (f32x4)0.f; }

    const float* z0 = z + ((size_t)b0 * 16 + l15) * KD + l4 * 8;
    const float* z1 = z + ((size_t)b1 * 16 + l15) * KD + l4 * 8;

#pragma unroll
    for (int ks = 0; ks < 8; ++ks) {
      const float4 a0 = *(const float4*)(z0 + ks * 32);
      const float4 a0b = *(const float4*)(z0 + ks * 32 + 4);
      const float4 a1 = *(const float4*)(z1 + ks * 32);
      const float4 a1b = *(const float4*)(z1 + ks * 32 + 4);
      union { uint4v u; short8 s; } c0v, c1v;
      c0v.u[0] = pkbf(a0.x, a0.y);  c0v.u[1] = pkbf(a0.z, a0.w);
      c0v.u[2] = pkbf(a0b.x, a0b.y); c0v.u[3] = pkbf(a0b.z, a0b.w);
      c1v.u[0] = pkbf(a1.x, a1.y);  c1v.u[1] = pkbf(a1.z, a1.w);
      c1v.u[2] = pkbf(a1b.x, a1b.y); c1v.u[3] = pkbf(a1b.z, a1b.w);
#pragma unroll
      for (int n = 0; n < 8; ++n) {
        union { ushort8 u; short8 s; } bv;
        bv.u = *(const ushort8*)&Bs[(n * 16 + l15) * KD +
                                    (((ks * 4 + l4) ^ (l15 & 7)) << 3)];
        acc0[n] = __builtin_amdgcn_mfma_f32_16x16x32_bf16(c0v.s, bv.s, acc0[n], 0, 0, 0);
        acc1[n] = __builtin_amdgcn_mfma_f32_16x16x32_bf16(c1v.s, bv.s, acc1[n], 0, 0, 0);
      }
    }

    // epilogue: one 16B store per lane per row, permuted cols j = l15*8+n
#pragma unroll
    for (int r = 0; r < 4; ++r) {
      uint4v q;
      q[0] = pkbf(acc0[0][r], acc0[1][r]); q[1] = pkbf(acc0[2][r], acc0[3][r]);
      q[2] = pkbf(acc0[4][r], acc0[5][r]); q[3] = pkbf(acc0[6][r], acc0[7][r]);
      *(uint4v*)(C + ((size_t)b0 * 16 + l4 * 4 + r) * NO + n0 + l15 * 8) = q;
      q[0] = pkbf(acc1[0][r], acc1[1][r]); q[1] = pkbf(acc1[2][r], acc1[3][r]);
      q[2] = pkbf(acc1[4][r], acc1[5][r]); q[3] = pkbf(acc1[6][r], acc1[7][r]);
      *(uint4v*)(C + ((size_t)b1 * 16 + l4 * 4 + r) * NO + n0 + l15 * 8) = q;
    }
  }
}

// ---- per-edge: out[e] = b2 + sum W2[h]*relu(A[s][h] + B[d][h] + b1[h]) ----
// C cols are permuted; load b1/W2 through hperm to match.
__global__ __launch_bounds__(256) void edge_mlp(const unsigned short* __restrict__ C,
                                                const int* __restrict__ ei,
                                                const float* __restrict__ b1,
                                                const float* __restrict__ W2,
                                                const float* __restrict__ b2,
                                                float* __restrict__ out) {
  const int t = threadIdx.x;
  const int lane = t & 63;
  const int g = lane >> 4;           // edge slot within wave (0..3)
  const int c0 = (lane & 15) * 16;   // stored-channel base for this lane
  float b1v[16], w2v[16];
#pragma unroll
  for (int i = 0; i < 16; ++i) {
    const int h = hperm(c0 + i);
    b1v[i] = b1[h]; w2v[i] = W2[h];
  }
  const float bias2 = b2[0];
  const int waveId = blockIdx.x * 4 + (t >> 6);
  const int nw = gridDim.x * 4;
  for (int e0 = waveId * 4; e0 < NE; e0 += nw * 4) {
    const int e = e0 + g;                 // NE % 4 == 0 -> always valid
    const int sn = ei[e];
    const int dn = ei[NE + e];
    const ushort8* ap = (const ushort8*)(C + (size_t)sn * NO + c0);
    const ushort8* bp = (const ushort8*)(C + (size_t)dn * NO + 256 + c0);
    ushort8 a0 = ap[0], a1 = ap[1];
    ushort8 v0 = bp[0], v1 = bp[1];
    float partial = 0.f;
#pragma unroll
    for (int j = 0; j < 8; ++j) {
      float h = bf2f(a0[j]) + bf2f(v0[j]) + b1v[j];
      h = fmaxf(h, 0.f);
      partial = fmaf(h, w2v[j], partial);
    }
#pragma unroll
    for (int j = 0; j < 8; ++j) {
      float h = bf2f(a1[j]) + bf2f(v1[j]) + b1v[8 + j];
      h = fmaxf(h, 0.f);
      partial = fmaf(h, w2v[8 + j], partial);
    }
    partial += __shfl_xor(partial, 8);
    partial += __shfl_xor(partial, 4);
    partial += __shfl_xor(partial, 2);
    partial += __shfl_xor(partial, 1);
    if ((lane & 15) == 0) out[e] = partial + bias2;
  }
}

extern "C" void kernel_launch(void* const* d_in, const int* in_sizes, int n_in,
                              void* d_out, int out_size, void* d_ws, size_t ws_size,
                              hipStream_t stream) {
  const float* z  = (const float*)d_in[0];
  const float* W1 = (const float*)d_in[1];
  const float* b1 = (const float*)d_in[2];
  const float* W2 = (const float*)d_in[3];
  const float* b2 = (const float*)d_in[4];
  const int*   ei = (const int*)d_in[5];
  float* out = (float*)d_out;

  unsigned short* C  = (unsigned short*)d_ws;          // 100000*512 bf16 = 102.4 MB
  unsigned short* Wt = C + (size_t)NN * NO;            // 512*256 bf16 = 256 KB

  prep_w<<<512, 256, 0, stream>>>(W1, Wt);
  gemm_zw<<<1024, 256, 0, stream>>>(z, Wt, C);
  edge_mlp<<<2048, 256, 0, stream>>>(C, ei, b1, W2, b2, out);
}

// Round 5
// 120.027 us; speedup vs baseline: 1.4725x; 1.0368x over previous
//
#include <hip/hip_runtime.h>

// LinkPredictor: out[e] = W2 . relu(W1s.z[src] + W1d.z[dst] + b1) + b2
// Factored: C = z @ [W1s|W1d]^T  (node GEMM, bf16 MFMA), then per-edge
// gather + fused add/relu/dot.  GEMM: B staged ONCE in LDS (64 KB,
// swizzled), A streamed global->reg with forced issue-early (all 32
// loads in flight, sched_barrier-pinned), zero per-K barriers.

#define NN 100000   // nodes
#define NE 300000   // edges
#define KD 256      // in channels (K)
#define NO 512      // 2*HID output cols (A | B)
#define BN 128      // cols per block
#define NSLOT 3125  // 100000 rows / 32 (pair-slots of 2x16-row bands)

typedef __attribute__((ext_vector_type(8))) short short8;
typedef __attribute__((ext_vector_type(8))) unsigned short ushort8;
typedef __attribute__((ext_vector_type(4))) float f32x4;
typedef __attribute__((ext_vector_type(4))) unsigned int uint4v;

__device__ __forceinline__ unsigned short f2bf(float f) {
  union { float f; unsigned int u; } v; v.f = f;
  unsigned int u = v.u;
  u += 0x7fffu + ((u >> 16) & 1u);   // RNE
  return (unsigned short)(u >> 16);
}
__device__ __forceinline__ float bf2f(unsigned short h) {
  union { unsigned int u; float f; } v; v.u = ((unsigned int)h) << 16;
  return v.f;
}
// pack 2 f32 -> {bf16(a) low, bf16(b) high} (round-half-up)
__device__ __forceinline__ unsigned int pkbf(float a, float b) {
  unsigned int ua = __float_as_uint(a) + 0x8000u;
  unsigned int ub = __float_as_uint(b) + 0x8000u;
  return __builtin_amdgcn_perm(ub, ua, 0x07060302u);
}
// stored-col -> hidden-channel permutation (within 0..255)
__device__ __forceinline__ int hperm(int s) {
  int j = s & 127;
  return (s & ~127) + ((j & 7) << 4) + (j >> 3);
}

// ---- repack W1 (f32 [256][512]) -> Wt (bf16 [512][256], K-contiguous) ----
__global__ void prep_w(const float* __restrict__ W1, unsigned short* __restrict__ Wt) {
  int idx = blockIdx.x * 256 + threadIdx.x;   // 512*256 = 131072
  int j = idx >> 8, k = idx & 255;
  float v = (j < 256) ? W1[j * 512 + k] : W1[(j - 256) * 512 + 256 + k];
  Wt[idx] = f2bf(v);
}

// ---- C[n][perm(j)] = sum_k z[n][k] * Wt[j][k] ----
__global__ __launch_bounds__(256, 2) void gemm_zw(const float* __restrict__ z,
                                                  const unsigned short* __restrict__ Wt,
                                                  unsigned short* __restrict__ C) {
  __shared__ unsigned short Bs[BN * KD];   // 64 KB

  // XCD-pinned: 4 nt-siblings of one m-group share blockIdx&7 (same XCD)
  const int b = blockIdx.x;            // 0..1023
  const int xcd = b & 7;
  const int q = b >> 3;                // 0..127
  const int nt = q & 3;
  const int mgrp = xcd * 32 + (q >> 2);  // 0..255
  const int n0 = nt * BN;

  const int t = threadIdx.x;
  const int w = t >> 6, lane = t & 63;
  const int l15 = lane & 15, l4 = lane >> 4;

  // ---- stage B once: Bs[row][chunk c stored at c^(row&7)], coalesced src
#pragma unroll
  for (int i = 0; i < 16; ++i) {
    const int id = t + 256 * i;        // 0..4095 16B-chunks
    const int row = id >> 5, c = id & 31;
    ushort8 v = *(const ushort8*)(Wt + (size_t)(n0 + row) * KD + c * 8);
    *(ushort8*)&Bs[row * KD + ((c ^ (row & 7)) << 3)] = v;
  }
  __syncthreads();                     // the ONLY barrier

  const int strm = mgrp * 4 + w;       // 0..1023 independent wave streams

  for (int s = strm; s < NSLOT; s += 1024) {
    // ---- issue ALL 32 A-loads for the 32-row pair-slot upfront ----
    const float* z0 = z + ((size_t)s * 32 + l15) * KD + l4 * 8;
    const float* z1 = z0 + (size_t)16 * KD;
    float4 za[8], zb[8], zc[8], zd[8];
#pragma unroll
    for (int ks = 0; ks < 8; ++ks) {
      za[ks] = *(const float4*)(z0 + ks * 32);
      zb[ks] = *(const float4*)(z0 + ks * 32 + 4);
      zc[ks] = *(const float4*)(z1 + ks * 32);
      zd[ks] = *(const float4*)(z1 + ks * 32 + 4);
    }
    __builtin_amdgcn_sched_barrier(0);   // pin: loads stay issued above

    f32x4 acc0[8], acc1[8];              // zeroing overlaps load latency
#pragma unroll
    for (int n = 0; n < 8; ++n) { acc0[n] = (f32x4)0.f; acc1[n] = (f32x4)0.f; }

#pragma unroll
    for (int ks = 0; ks < 8; ++ks) {
      union { uint4v u; short8 s; } c0v, c1v;
      c0v.u[0] = pkbf(za[ks].x, za[ks].y); c0v.u[1] = pkbf(za[ks].z, za[ks].w);
      c0v.u[2] = pkbf(zb[ks].x, zb[ks].y); c0v.u[3] = pkbf(zb[ks].z, zb[ks].w);
      c1v.u[0] = pkbf(zc[ks].x, zc[ks].y); c1v.u[1] = pkbf(zc[ks].z, zc[ks].w);
      c1v.u[2] = pkbf(zd[ks].x, zd[ks].y); c1v.u[3] = pkbf(zd[ks].z, zd[ks].w);
#pragma unroll
      for (int n = 0; n < 8; ++n) {
        union { ushort8 u; short8 s; } bv;
        bv.u = *(const ushort8*)&Bs[(n * 16 + l15) * KD +
                                    (((ks * 4 + l4) ^ (l15 & 7)) << 3)];
        acc0[n] = __builtin_amdgcn_mfma_f32_16x16x32_bf16(c0v.s, bv.s, acc0[n], 0, 0, 0);
        acc1[n] = __builtin_amdgcn_mfma_f32_16x16x32_bf16(c1v.s, bv.s, acc1[n], 0, 0, 0);
      }
    }

    // epilogue: one 16B store per lane per row, permuted cols j = l15*8+n
#pragma unroll
    for (int r = 0; r < 4; ++r) {
      uint4v p;
      p[0] = pkbf(acc0[0][r], acc0[1][r]); p[1] = pkbf(acc0[2][r], acc0[3][r]);
      p[2] = pkbf(acc0[4][r], acc0[5][r]); p[3] = pkbf(acc0[6][r], acc0[7][r]);
      *(uint4v*)(C + ((size_t)s * 32 + l4 * 4 + r) * NO + n0 + l15 * 8) = p;
      p[0] = pkbf(acc1[0][r], acc1[1][r]); p[1] = pkbf(acc1[2][r], acc1[3][r]);
      p[2] = pkbf(acc1[4][r], acc1[5][r]); p[3] = pkbf(acc1[6][r], acc1[7][r]);
      *(uint4v*)(C + ((size_t)s * 32 + 16 + l4 * 4 + r) * NO + n0 + l15 * 8) = p;
    }
  }
}

// ---- per-edge: out[e] = b2 + sum W2[h]*relu(A[s][h] + B[d][h] + b1[h]) ----
// C cols are permuted; load b1/W2 through hperm to match.
__global__ __launch_bounds__(256) void edge_mlp(const unsigned short* __restrict__ C,
                                                const int* __restrict__ ei,
                                                const float* __restrict__ b1,
                                                const float* __restrict__ W2,
                                                const float* __restrict__ b2,
                                                float* __restrict__ out) {
  const int t = threadIdx.x;
  const int lane = t & 63;
  const int g = lane >> 4;           // edge slot within wave (0..3)
  const int c0 = (lane & 15) * 16;   // stored-channel base for this lane
  float b1v[16], w2v[16];
#pragma unroll
  for (int i = 0; i < 16; ++i) {
    const int h = hperm(c0 + i);
    b1v[i] = b1[h]; w2v[i] = W2[h];
  }
  const float bias2 = b2[0];
  const int waveId = blockIdx.x * 4 + (t >> 6);
  const int nw = gridDim.x * 4;
  for (int e0 = waveId * 4; e0 < NE; e0 += nw * 4) {
    const int e = e0 + g;                 // NE % 4 == 0 -> always valid
    const int sn = ei[e];
    const int dn = ei[NE + e];
    const ushort8* ap = (const ushort8*)(C + (size_t)sn * NO + c0);
    const ushort8* bp = (const ushort8*)(C + (size_t)dn * NO + 256 + c0);
    ushort8 a0 = ap[0], a1 = ap[1];
    ushort8 v0 = bp[0], v1 = bp[1];
    float partial = 0.f;
#pragma unroll
    for (int j = 0; j < 8; ++j) {
      float h = bf2f(a0[j]) + bf2f(v0[j]) + b1v[j];
      h = fmaxf(h, 0.f);
      partial = fmaf(h, w2v[j], partial);
    }
#pragma unroll
    for (int j = 0; j < 8; ++j) {
      float h = bf2f(a1[j]) + bf2f(v1[j]) + b1v[8 + j];
      h = fmaxf(h, 0.f);
      partial = fmaf(h, w2v[8 + j], partial);
    }
    partial += __shfl_xor(partial, 8);
    partial += __shfl_xor(partial, 4);
    partial += __shfl_xor(partial, 2);
    partial += __shfl_xor(partial, 1);
    if ((lane & 15) == 0) out[e] = partial + bias2;
  }
}

extern "C" void kernel_launch(void* const* d_in, const int* in_sizes, int n_in,
                              void* d_out, int out_size, void* d_ws, size_t ws_size,
                              hipStream_t stream) {
  const float* z  = (const float*)d_in[0];
  const float* W1 = (const float*)d_in[1];
  const float* b1 = (const float*)d_in[2];
  const float* W2 = (const float*)d_in[3];
  const float* b2 = (const float*)d_in[4];
  const int*   ei = (const int*)d_in[5];
  float* out = (float*)d_out;

  unsigned short* C  = (unsigned short*)d_ws;          // 100000*512 bf16 = 102.4 MB
  unsigned short* Wt = C + (size_t)NN * NO;            // 512*256 bf16 = 256 KB

  prep_w<<<512, 256, 0, stream>>>(W1, Wt);
  gemm_zw<<<1024, 256, 0, stream>>>(z, Wt, C);
  edge_mlp<<<2048, 256, 0, stream>>>(C, ei, b1, W2, b2, out);
}

// Round 6
// 109.279 us; speedup vs baseline: 1.6173x; 1.0984x over previous
//
#include <hip/hip_runtime.h>

// LinkPredictor: out[e] = W2 . relu(W1s.z[src] + W1d.z[dst] + b1) + b2
// Factored: C = z @ [W1s|W1d]^T  (node GEMM, bf16 MFMA), then per-edge
// gather + fused add/relu/dot.
// GEMM v6: B staged ONCE in LDS (64 KB swizzled); A streamed via
// global_load_lds into per-wave private LDS double-buffers with counted
// per-wave vmcnt waits — zero __syncthreads in the K-pipeline, loads in
// flight cost no VGPRs.

#define NN 100000   // nodes
#define NE 300000   // edges
#define KD 256      // in channels (K)
#define NO 512      // 2*HID output cols (A | B)
#define BN 128      // cols per block
#define NSLOT 3125  // 100000 / 32 rows per slot
#define NSTREAM 256 // wave streams (256 blocks x 4 waves / 4 nt-siblings)

typedef __attribute__((ext_vector_type(8))) short short8;
typedef __attribute__((ext_vector_type(8))) unsigned short ushort8;
typedef __attribute__((ext_vector_type(4))) float f32x4;
typedef __attribute__((ext_vector_type(4))) unsigned int uint4v;

__device__ __forceinline__ unsigned short f2bf(float f) {
  union { float f; unsigned int u; } v; v.f = f;
  unsigned int u = v.u;
  u += 0x7fffu + ((u >> 16) & 1u);   // RNE
  return (unsigned short)(u >> 16);
}
__device__ __forceinline__ float bf2f(unsigned short h) {
  union { unsigned int u; float f; } v; v.u = ((unsigned int)h) << 16;
  return v.f;
}
// pack 2 f32 -> {bf16(a) low, bf16(b) high} (round-half-up)
__device__ __forceinline__ unsigned int pkbf(float a, float b) {
  unsigned int ua = __float_as_uint(a) + 0x8000u;
  unsigned int ub = __float_as_uint(b) + 0x8000u;
  return __builtin_amdgcn_perm(ub, ua, 0x07060302u);
}
// stored-col -> hidden-channel permutation (within 0..255)
__device__ __forceinline__ int hperm(int s) {
  int j = s & 127;
  return (s & ~127) + ((j & 7) << 4) + (j >> 3);
}

// ---- repack W1 (f32 [256][512]) -> Wt (bf16 [512][256], K-contiguous) ----
__global__ void prep_w(const float* __restrict__ W1, unsigned short* __restrict__ Wt) {
  int idx = blockIdx.x * 256 + threadIdx.x;   // 512*256 = 131072
  int j = idx >> 8, k = idx & 255;
  float v = (j < 256) ? W1[j * 512 + k] : W1[(j - 256) * 512 + 256 + k];
  Wt[idx] = f2bf(v);
}

// ---- C[n][perm(j)] = sum_k z[n][k] * Wt[j][k] ----
__global__ __launch_bounds__(256, 1) void gemm_zw(const float* __restrict__ z,
                                                  const unsigned short* __restrict__ Wt,
                                                  unsigned short* __restrict__ C) {
  __shared__ unsigned short Bs[BN * KD];   // 64 KB
  __shared__ float Aw[4][2][2048];         // 4 waves x dbuf x 8 KB = 64 KB

  // XCD-pinned: 4 nt-siblings of one m-group share blockIdx&7 (same XCD)
  const int b = blockIdx.x;            // 0..255
  const int xcd = b & 7;
  const int q = b >> 3;                // 0..31
  const int nt = q & 3;
  const int mgrp = xcd * 8 + (q >> 2); // 0..63
  const int n0 = nt * BN;

  const int t = threadIdx.x;
  const int w = t >> 6, lane = t & 63;
  const int l15 = lane & 15, l4 = lane >> 4;

  // ---- stage B once: Bs[row][chunk c stored at c^(row&7)], coalesced src
#pragma unroll
  for (int i = 0; i < 16; ++i) {
    const int id = t + 256 * i;        // 0..4095 16B-chunks
    const int row = id >> 5, c = id & 31;
    ushort8 v = *(const ushort8*)(Wt + (size_t)(n0 + row) * KD + c * 8);
    *(ushort8*)&Bs[row * KD + ((c ^ (row & 7)) << 3)] = v;
  }
  __syncthreads();                     // the ONLY barrier

  const int strm = mgrp * 4 + w;       // 0..255 independent wave streams

  for (int s = strm; s < NSLOT; s += NSTREAM) {
    // per-lane global srcs for the 8 gll issues (source pre-swizzled so LDS
    // stays gll-linear but ds_read is conflict-free: chunk (l&15)^(row&15))
    const float* gp[8];
#pragma unroll
    for (int j = 0; j < 8; ++j) {
      const int r = j * 4 + (lane >> 4);
      gp[j] = z + (size_t)(s * 32 + r) * KD + (((lane & 15) ^ (r & 15)) << 2);
    }
    float* Ab0 = &Aw[w][0][0];
    float* Ab1 = &Aw[w][1][0];

#define ISSUE(cc, dst)                                                             \
    { _Pragma("unroll")                                                            \
      for (int j = 0; j < 8; ++j)                                                  \
        __builtin_amdgcn_global_load_lds(                                          \
          (const __attribute__((address_space(1))) unsigned int*)(gp[j] + (cc) * 64), \
          (__attribute__((address_space(3))) unsigned int*)((dst) + j * 256),      \
          16, 0, 0); }                                                             \
    __builtin_amdgcn_sched_barrier(0);

    ISSUE(0, Ab0)
    ISSUE(1, Ab1)

    f32x4 acc0[8], acc1[8];
#pragma unroll
    for (int n = 0; n < 8; ++n) { acc0[n] = (f32x4)0.f; acc1[n] = (f32x4)0.f; }

    // per chunk: wait (positional, in-order vmcnt) -> ds_read A -> lgkm drain
    // -> prefetch c+2 into the just-freed buffer -> pack -> MFMA
#define CHUNK(cc, Ab, WAITN, PREF)                                                 \
    {                                                                              \
      asm volatile("s_waitcnt vmcnt(" #WAITN ")" ::: "memory");                    \
      __builtin_amdgcn_sched_barrier(0);                                           \
      float4 av[8];                                                                \
      _Pragma("unroll")                                                            \
      for (int ks = 0; ks < 2; ++ks) {                                             \
        _Pragma("unroll")                                                          \
        for (int bd = 0; bd < 2; ++bd) {                                           \
          const int row = bd * 16 + l15;                                           \
          const int gc0 = ks * 8 + l4 * 2;                                         \
          av[ks*4+bd*2+0] = *(const float4*)&(Ab)[row*64 + ((gc0 ^ l15) << 2)];    \
          av[ks*4+bd*2+1] = *(const float4*)&(Ab)[row*64 + (((gc0+1) ^ l15) << 2)];\
        }                                                                          \
      }                                                                            \
      asm volatile("s_waitcnt lgkmcnt(0)" ::: "memory");                           \
      __builtin_amdgcn_sched_barrier(0);                                           \
      if (PREF) ISSUE((cc) + 2, Ab)                                                \
      _Pragma("unroll")                                                            \
      for (int ks = 0; ks < 2; ++ks) {                                             \
        union { uint4v u; short8 s; } a0v, a1v;                                    \
        a0v.u[0] = pkbf(av[ks*4+0].x, av[ks*4+0].y);                               \
        a0v.u[1] = pkbf(av[ks*4+0].z, av[ks*4+0].w);                               \
        a0v.u[2] = pkbf(av[ks*4+1].x, av[ks*4+1].y);                               \
        a0v.u[3] = pkbf(av[ks*4+1].z, av[ks*4+1].w);                               \
        a1v.u[0] = pkbf(av[ks*4+2].x, av[ks*4+2].y);                               \
        a1v.u[1] = pkbf(av[ks*4+2].z, av[ks*4+2].w);                               \
        a1v.u[2] = pkbf(av[ks*4+3].x, av[ks*4+3].y);                               \
        a1v.u[3] = pkbf(av[ks*4+3].z, av[ks*4+3].w);                               \
        const int kc = ((cc) * 2 + ks) * 4 + l4;                                   \
        _Pragma("unroll")                                                          \
        for (int n = 0; n < 8; ++n) {                                              \
          union { ushort8 u; short8 s; } bv;                                       \
          bv.u = *(const ushort8*)&Bs[(n*16 + l15)*KD + ((kc ^ (l15 & 7)) << 3)];  \
          acc0[n] = __builtin_amdgcn_mfma_f32_16x16x32_bf16(a0v.s, bv.s, acc0[n], 0,0,0); \
          acc1[n] = __builtin_amdgcn_mfma_f32_16x16x32_bf16(a1v.s, bv.s, acc1[n], 0,0,0); \
        }                                                                          \
      }                                                                            \
    }

    CHUNK(0, Ab0, 8, 1)
    CHUNK(1, Ab1, 8, 1)
    CHUNK(2, Ab0, 8, 0)
    CHUNK(3, Ab1, 0, 0)
#undef CHUNK
#undef ISSUE

    // epilogue: one 16B store per lane per row, permuted cols j = l15*8+n
#pragma unroll
    for (int r = 0; r < 4; ++r) {
      uint4v p;
      p[0] = pkbf(acc0[0][r], acc0[1][r]); p[1] = pkbf(acc0[2][r], acc0[3][r]);
      p[2] = pkbf(acc0[4][r], acc0[5][r]); p[3] = pkbf(acc0[6][r], acc0[7][r]);
      *(uint4v*)(C + ((size_t)s * 32 + l4 * 4 + r) * NO + n0 + l15 * 8) = p;
      p[0] = pkbf(acc1[0][r], acc1[1][r]); p[1] = pkbf(acc1[2][r], acc1[3][r]);
      p[2] = pkbf(acc1[4][r], acc1[5][r]); p[3] = pkbf(acc1[6][r], acc1[7][r]);
      *(uint4v*)(C + ((size_t)s * 32 + 16 + l4 * 4 + r) * NO + n0 + l15 * 8) = p;
    }
  }
}

// ---- per-edge: out[e] = b2 + sum W2[h]*relu(A[s][h] + B[d][h] + b1[h]) ----
// C cols are permuted; load b1/W2 through hperm to match.
__global__ __launch_bounds__(256) void edge_mlp(const unsigned short* __restrict__ C,
                                                const int* __restrict__ ei,
                                                const float* __restrict__ b1,
                                                const float* __restrict__ W2,
                                                const float* __restrict__ b2,
                                                float* __restrict__ out) {
  const int t = threadIdx.x;
  const int lane = t & 63;
  const int g = lane >> 4;           // edge slot within wave (0..3)
  const int c0 = (lane & 15) * 16;   // stored-channel base for this lane
  float b1v[16], w2v[16];
#pragma unroll
  for (int i = 0; i < 16; ++i) {
    const int h = hperm(c0 + i);
    b1v[i] = b1[h]; w2v[i] = W2[h];
  }
  const float bias2 = b2[0];
  const int waveId = blockIdx.x * 4 + (t >> 6);
  const int nw = gridDim.x * 4;
  for (int e0 = waveId * 4; e0 < NE; e0 += nw * 4) {
    const int e = e0 + g;                 // NE % 4 == 0 -> always valid
    const int sn = ei[e];
    const int dn = ei[NE + e];
    const ushort8* ap = (const ushort8*)(C + (size_t)sn * NO + c0);
    const ushort8* bp = (const ushort8*)(C + (size_t)dn * NO + 256 + c0);
    ushort8 a0 = ap[0], a1 = ap[1];
    ushort8 v0 = bp[0], v1 = bp[1];
    float partial = 0.f;
#pragma unroll
    for (int j = 0; j < 8; ++j) {
      float h = bf2f(a0[j]) + bf2f(v0[j]) + b1v[j];
      h = fmaxf(h, 0.f);
      partial = fmaf(h, w2v[j], partial);
    }
#pragma unroll
    for (int j = 0; j < 8; ++j) {
      float h = bf2f(a1[j]) + bf2f(v1[j]) + b1v[8 + j];
      h = fmaxf(h, 0.f);
      partial = fmaf(h, w2v[8 + j], partial);
    }
    partial += __shfl_xor(partial, 8);
    partial += __shfl_xor(partial, 4);
    partial += __shfl_xor(partial, 2);
    partial += __shfl_xor(partial, 1);
    if ((lane & 15) == 0) out[e] = partial + bias2;
  }
}

extern "C" void kernel_launch(void* const* d_in, const int* in_sizes, int n_in,
                              void* d_out, int out_size, void* d_ws, size_t ws_size,
                              hipStream_t stream) {
  const float* z  = (const float*)d_in[0];
  const float* W1 = (const float*)d_in[1];
  const float* b1 = (const float*)d_in[2];
  const float* W2 = (const float*)d_in[3];
  const float* b2 = (const float*)d_in[4];
  const int*   ei = (const int*)d_in[5];
  float* out = (float*)d_out;

  unsigned short* C  = (unsigned short*)d_ws;          // 100000*512 bf16 = 102.4 MB
  unsigned short* Wt = C + (size_t)NN * NO;            // 512*256 bf16 = 256 KB

  prep_w<<<512, 256, 0, stream>>>(W1, Wt);
  gemm_zw<<<256, 256, 0, stream>>>(z, Wt, C);          // 1 block/CU, all resident
  edge_mlp<<<2048, 256, 0, stream>>>(C, ei, b1, W2, b2, out);
}